// Round 2
// baseline (225.122 us; speedup 1.0000x reference)
//
#include <hip/hip_runtime.h>

// CropConv on MI355X: mask degenerates to all-True -> pure stride-2 3x3 conv.
// Implicit GEMM: M=COUT=256, N=B*OH*OW=32768, K=CIN*9=2304, f16 MFMA 32x32x16.
//
// R2: (a) T2 ci-half XOR swizzle on ws and xs -> 4-way ds_read_b128 conflicts
// become free 2-way; swizzle is lane-constant, folded into precomputed bases.
// (b) depth-2 x prefetch (two register banks, 2-cc window) so HBM latency is
// fully covered at the vmcnt wait. (c) non-draining barriers (lgkmcnt(0) +
// raw s_barrier) so prefetch loads stay in flight across barriers.

#define B_   32
#define CIN  256
#define COUT 256
#define H_   64
#define W_   64
#define OH   32
#define OW   32

typedef _Float16 f16;
typedef _Float16 half8 __attribute__((ext_vector_type(8)));
typedef float    floatx16 __attribute__((ext_vector_type(16)));

// Pre-pass: repack fp32 weights [256][256][3][3] -> f16 in d_ws with layout
// [co_t 2][cc 16][khw 9][co_l 128][ci_l 16]  (1,179,648 B)
__global__ __launch_bounds__(256) void repack_w_kernel(const float* __restrict__ w,
                                                       f16* __restrict__ rp) {
  int o = blockIdx.x * 256 + threadIdx.x;     // 589824 total, exact
  int ci_l = o & 15;
  int tt = o >> 4;
  int co_l = tt & 127; tt >>= 7;
  int khw = tt % 9;    tt /= 9;
  int cc   = tt & 15;  tt >>= 4;
  int co_t = tt;                               // 0..1
  int co = co_t * 128 + co_l;
  int ci = cc * 16 + ci_l;
  rp[o] = (f16)w[(co * CIN + ci) * 9 + khw];
}

// Non-draining workgroup barrier: LDS ops flushed, VMEM loads stay in flight.
static __device__ __forceinline__ void wg_barrier() {
  __builtin_amdgcn_sched_barrier(0);
  asm volatile("s_waitcnt lgkmcnt(0)" ::: "memory");
  __builtin_amdgcn_s_barrier();
  __builtin_amdgcn_sched_barrier(0);
}

// LDS geometry (f16 units):
//  ws: [khw 9][co_l 128][ci 16], swizzled: off = khw*2048 + co_l*16 + (ci ^ (co_l&8))
//  xs: 2 buffers of 9520 f16; per buffer: even plane [0,4752), pad 8, odd plane
//      [4760, 9512). Element (p,r,idx,ci): p*4760 + r*528 + idx*16 + (ci ^ (idx&8))
__global__ __launch_bounds__(256, 2) void conv_mfma_kernel(
    const float* __restrict__ x, const f16* __restrict__ rp,
    float* __restrict__ out) {
  __shared__ __align__(16) f16 ws[18432];      // 36864 B
  __shared__ __align__(16) f16 xs[19040];      // 38080 B (2 x 9520)

  const int t    = threadIdx.x;
  const int lane = t & 63;
  const int wave = t >> 6;
  const int wm   = wave >> 1;   // co 64-half within 128
  const int wn   = wave & 1;    // n 64-half within 128 (= 2 output rows)

  const int blk  = blockIdx.x;  // 512
  const int b    = blk >> 4;
  const int rem  = blk & 15;
  const int co_t = rem >> 3;
  const int oh0  = (rem & 7) << 2;
  const int ih0  = 2 * oh0 - 1;

  const float* xb  = x + (size_t)b * CIN * H_ * W_;
  const f16*   rpb = rp + (size_t)co_t * (16 * 9 * 128 * 16);

  const int iw  = t & 63;                             // staging column
  const int rru = __builtin_amdgcn_readfirstlane(t >> 6);  // staging row group
  const int k0  = (lane >> 5) * 8;
  const int ml  = lane & 31;
  const int p_st   = iw & 1;                          // staging plane
  const int idx_st = (iw + p_st) >> 1;                // staging idx within plane
  const int gx     = (idx_st >> 3) & 1;               // write-side ci-half XOR

  f16* const xs0 = xs;
  f16* const xs1 = xs + 9520;

  floatx16 acc[2][2];
#pragma unroll
  for (int mi = 0; mi < 2; ++mi)
#pragma unroll
    for (int nj = 0; nj < 2; ++nj)
#pragma unroll
      for (int i = 0; i < 16; ++i) acc[mi][nj][i] = 0.f;

  // prefetch registers: two x banks (depth-2), one w bank (depth-1)
  float xva[3][2][8], xvb[3][2][8];
  half8 wv[9];

  auto load_x = [&](float (&xv)[3][2][8], int cc) {
    const float* bcc = xb + (size_t)cc * 16 * 4096;
#pragma unroll
    for (int it = 0; it < 3; ++it) {
      const int r = rru + it * 4;                     // wave-uniform
      if (r < 9) {
        const int ih = ih0 + r;
        if (ih >= 0) {
          const float* p0 = bcc + (size_t)ih * 64 + iw;
#pragma unroll
          for (int g = 0; g < 2; ++g)
#pragma unroll
            for (int c = 0; c < 8; ++c)
              xv[it][g][c] = p0[(size_t)(g * 8 + c) * 4096];
        } else {
#pragma unroll
          for (int g = 0; g < 2; ++g)
#pragma unroll
            for (int c = 0; c < 8; ++c) xv[it][g][c] = 0.f;
        }
      }
    }
  };

  auto load_w = [&](int cc) {
    const half8* src = (const half8*)(rpb + (size_t)cc * 18432);
#pragma unroll
    for (int i = 0; i < 9; ++i) wv[i] = src[t + i * 256];
  };

  auto write_x = [&](float (&xv)[3][2][8], f16* xoth) {
    f16* d = xoth + p_st * 4760 + idx_st * 16;
#pragma unroll
    for (int it = 0; it < 3; ++it) {
      const int r = rru + it * 4;
      if (r < 9) {
#pragma unroll
        for (int g = 0; g < 2; ++g) {
          half8 v;
#pragma unroll
          for (int c = 0; c < 8; ++c) v[c] = (f16)xv[it][g][c];
          *(half8*)&d[r * 528 + (g ^ gx) * 8] = v;
        }
      }
    }
  };

  const int colw = (t >> 1) & 127;
  f16* const wdst = ws + colw * 16 + (((t & 1) * 8) ^ (colw & 8));
  auto write_w = [&]() {
#pragma unroll
    for (int i = 0; i < 9; ++i) *(half8*)&wdst[i * 2048] = wv[i];
  };

  // swizzled, lane-constant read bases
  const f16* const Aw = ws + wm * 1024 + ml * 16 + (k0 ^ (ml & 8));

  auto compute = [&](const f16* xcur) {
    const f16* Be  = xcur + wn * 2112 + ml * 16 + (k0 ^ (ml & 8));     // even plane, idx=ml
    const f16* Bo1 = Be + 4760;                                        // odd plane, idx=ml
    const f16* Bo2 = xcur + 4760 + wn * 2112 + (ml + 1) * 16 + (k0 ^ ((ml + 1) & 8));
    __builtin_amdgcn_s_setprio(1);
#pragma unroll
    for (int kh = 0; kh < 3; ++kh) {
#pragma unroll
      for (int kw = 0; kw < 3; ++kw) {
        const int khw = kh * 3 + kw;
        half8 a0 = *(const half8*)&Aw[khw * 2048];
        half8 a1 = *(const half8*)&Aw[khw * 2048 + 512];
        const f16* Bp = (kw == 0) ? Bo1 : (kw == 1) ? Be : Bo2;
#pragma unroll
        for (int nj = 0; nj < 2; ++nj) {
          half8 bf = *(const half8*)&Bp[nj * 1056 + kh * 528];
          acc[0][nj] = __builtin_amdgcn_mfma_f32_32x32x16_f16(a0, bf, acc[0][nj], 0, 0, 0);
          acc[1][nj] = __builtin_amdgcn_mfma_f32_32x32x16_f16(a1, bf, acc[1][nj], 0, 0, 0);
        }
      }
    }
    __builtin_amdgcn_s_setprio(0);
  };

  // zero the odd-plane pad column (iw = -1 -> idx 0) of BOTH buffers, once
  if (t < 144) {
    const int r = t >> 4, ci = t & 15;
    xs0[4760 + r * 528 + ci] = (f16)0.f;
    xs1[4760 + r * 528 + ci] = (f16)0.f;
  }

  // prologue: stage cc=0; fill prefetch banks (A->1, B->2, wv->1)
  load_x(xva, 0); load_w(0);
  write_x(xva, xs0);
  write_w();
  load_x(xva, 1);
  load_x(xvb, 2);
  load_w(1);
  __syncthreads();   // one full drain, outside the hot loop

#pragma unroll 1
  for (int cc = 0; cc < 16; cc += 2) {
    // even sub-iter: compute xs0(cc); stage cc+1 from bank A
    compute(xs0);
    write_x(xva, xs1);                  // cc+1 (loads issued 2 sub-iters ago)
    if (cc + 3 < 16) load_x(xva, cc + 3);
    wg_barrier();                       // xs1 visible; ws(cc) reads done
    write_w();                          // ws <- cc+1
    if (cc + 2 < 16) load_w(cc + 2);
    wg_barrier();                       // ws(cc+1) visible

    // odd sub-iter: compute xs1(cc+1); stage cc+2 from bank B
    compute(xs1);
    if (cc + 2 < 16) write_x(xvb, xs0);
    if (cc + 4 < 16) load_x(xvb, cc + 4);
    wg_barrier();
    if (cc + 2 < 16) write_w();
    if (cc + 3 < 16) load_w(cc + 3);
    wg_barrier();
  }

  // ---- epilogue: C/D col=lane&31 (=ow), row=(reg&3)+8*(reg>>2)+4*(lane>>5) ----
  const int col = ml;
  const int rowbase = (lane >> 5) * 4;
  float* ob = out + ((size_t)b * COUT + co_t * 128 + wm * 64) * (OH * OW);
#pragma unroll
  for (int mi = 0; mi < 2; ++mi) {
#pragma unroll
    for (int nj = 0; nj < 2; ++nj) {
      const int oh = oh0 + wn * 2 + nj;
#pragma unroll
      for (int r = 0; r < 16; ++r) {
        const int row = mi * 32 + (r & 3) + 8 * (r >> 2) + rowbase;
        ob[(size_t)row * (OH * OW) + oh * OW + col] = acc[mi][nj][r];
      }
    }
  }
}

extern "C" void kernel_launch(void* const* d_in, const int* in_sizes, int n_in,
                              void* d_out, int out_size, void* d_ws, size_t ws_size,
                              hipStream_t stream) {
  const float* x = (const float*)d_in[0];   // [32][256][64][64] fp32
  const float* w = (const float*)d_in[1];   // [256][256][3][3]  fp32
  float* out = (float*)d_out;               // [32][256][32][32] fp32
  f16* rp = (f16*)d_ws;                     // 1.18 MB repacked f16 weights

  repack_w_kernel<<<2304, 256, 0, stream>>>(w, rp);
  conv_mfma_kernel<<<512, 256, 0, stream>>>(x, rp, out);
}